// Round 5
// baseline (37.926 us; speedup 1.0000x reference)
//
#include <hip/hip_runtime.h>
#include <math.h>

#define HH 256
#define WW 256
#define BB 32
#define NW 8  // 256 rows = 8 x u32 words per column bitmask

// ---------------------------------------------------------------------------
// Kernel A: build column bitmasks.  P bit = (pred > 0.5), T bit = (target==1).
// Grid: BB*NW*4 = 1024 blocks; block = (b, word-row j, column-quarter wq).
// ---------------------------------------------------------------------------
__global__ __launch_bounds__(256) void bitmask_kernel(
    const float* __restrict__ pred, const float* __restrict__ tgt,
    unsigned int* __restrict__ P, unsigned int* __restrict__ T) {
  const int b  = blockIdx.x >> 5;
  const int j  = (blockIdx.x >> 2) & 7;
  const int wq = blockIdx.x & 3;
  const int r    = threadIdx.x >> 6;   // wave id: row-subset (8 rows)
  const int lane = threadIdx.x & 63;
  const int col  = wq * 64 + lane;
  const int row0 = j * 32 + r * 8;

  const float* pin = pred + (size_t)b * (HH * WW) + row0 * WW + col;
  const float* tin = tgt  + (size_t)b * (HH * WW) + row0 * WW + col;
  unsigned int pb = 0, tb = 0;
#pragma unroll
  for (int i = 0; i < 8; ++i) {
    pb |= (pin[i * WW] > 0.5f ? 1u : 0u) << i;
    tb |= (tin[i * WW] == 1.0f ? 1u : 0u) << i;
  }

  __shared__ unsigned int sP[4][64], sT[4][64];
  sP[r][lane] = pb << (r * 8);
  sT[r][lane] = tb << (r * 8);
  __syncthreads();
  if (r == 0) {
    P[((size_t)b * NW + j) * WW + col] =
        sP[0][lane] | sP[1][lane] | sP[2][lane] | sP[3][lane];
    T[((size_t)b * NW + j) * WW + col] =
        sT[0][lane] | sT[1][lane] | sT[2][lane] | sT[3][lane];
  }
}

// ---------------------------------------------------------------------------
// Kernel A2: per-column 1D distance to nearest DIFFERING pixel, via edge
// masks.  E_p = (bit p != bit p+1).  Nearest differing below query q is the
// highest edge < q; above is the lowest edge >= q.  Two 32-step register
// cndmask chains per thread (seeded by cross-word clz/ctz carries), fully
// unrolled -> no scratch, no serial global round trips.  Writes dd^2 as f32.
// Grid: BB*16 blocks; block = (b, map*8+j); thread = column w.
// ---------------------------------------------------------------------------
__global__ __launch_bounds__(256) void coledt_kernel(
    const unsigned int* __restrict__ P, const unsigned int* __restrict__ T,
    float* __restrict__ DP2, float* __restrict__ DT2) {
  const int b  = blockIdx.x >> 4;
  const int mj = blockIdx.x & 15;
  const int mp = mj >> 3;        // 0: pred mask, 1: target mask
  const int j  = mj & 7;         // 32-row word this thread produces
  const int w  = threadIdx.x;

  const unsigned int* M = mp ? T : P;
  float* OUT = mp ? DT2 : DP2;

  unsigned int Wd[NW];
#pragma unroll
  for (int jj = 0; jj < NW; ++jj)
    Wd[jj] = M[((size_t)b * NW + jj) * WW + w];

  // edge words: bit p of E[jj] = (bit p != bit p+1), global pair (32jj+p, +1)
  unsigned int E[NW];
#pragma unroll
  for (int jj = 0; jj < NW - 1; ++jj)
    E[jj] = Wd[jj] ^ ((Wd[jj] >> 1) | (Wd[jj + 1] << 31));
  E[NW - 1] = (Wd[NW - 1] ^ (Wd[NW - 1] >> 1)) & 0x7FFFFFFFu;  // no edge at 255

  // select this block's word (j is uniform; keep indices static)
  unsigned int EJ = 0, EJm1 = 0;
#pragma unroll
  for (int jj = 0; jj < NW; ++jj) {
    if (j == jj) EJ = E[jj];
    if (j - 1 == jj) EJm1 = E[jj];
  }

  // down-carry: highest edge position <= base-1 among words below
  int emax = -100000;
#pragma unroll
  for (int jj = 0; jj < NW - 1; ++jj)
    if (jj < j && E[jj]) emax = 32 * jj + 31 - __builtin_clz(E[jj]);
  int D = (j * 32 - 1) - emax;
  if (D > 513) D = 513;

  // up-carry: lowest edge position >= base+32 among words above
  int emin = 100000;
#pragma unroll
  for (int jj = NW - 1; jj >= 1; --jj)
    if (jj > j && E[jj]) emin = 32 * jj + __builtin_ctz(E[jj]);
  int U = (emin + 1) - (j * 32 + 32);
  if (U > 513) U = 513;

  // query-aligned edge word for the down chain: bit i = edge at (base+i-1)
  const unsigned int EQ = (EJ << 1) | (j ? (EJm1 >> 31) : 0u);

  // down chain (ascending), pack u16 pairs
  unsigned int dn[16];
#pragma unroll
  for (int i = 0; i < 32; ++i) {
    D = ((EQ >> i) & 1u) ? 1 : (D + 1);
    if (i & 1) dn[i >> 1] |= (unsigned int)D << 16;
    else       dn[i >> 1] = (unsigned int)D;
  }

  // up chain (descending) + combine + coalesced f32 store of dd^2
  const size_t obase = (size_t)b * (HH * WW) + (size_t)(j * 32) * WW + w;
#pragma unroll
  for (int i = 31; i >= 0; --i) {
    U = ((EJ >> i) & 1u) ? 1 : (U + 1);
    int dnv = (int)((dn[i >> 1] >> ((i & 1) * 16)) & 0xFFFFu);
    int g = min(min(dnv, U), 512);       // cap = H+W (exact, incl. empty cols)
    OUT[obase + (size_t)i * WW] = (float)(g * g);
  }
}

// ---------------------------------------------------------------------------
// Kernel B: per-row min-plus (exact early exit) + fused loss + block reduce.
// Thread y: 2 f32 dd^2 loads + 2 own-bit word loads replace the old 200-VALU
// per-thread bitmask scan (now hoisted to kernel A2, once per column).
// ---------------------------------------------------------------------------
__global__ __launch_bounds__(256) void minplus_kernel(
    const unsigned int* __restrict__ P, const unsigned int* __restrict__ T,
    const float* __restrict__ DP2, const float* __restrict__ DT2,
    float* __restrict__ partial) {
  const int row = blockIdx.x;     // b*HH + h
  const int b = row >> 8;
  const int h = row & 255;
  const int y = threadIdx.x;
  const int wj = h >> 5, bi = h & 31;

  const size_t ibase = (size_t)b * (HH * WW) + (size_t)h * WW + y;
  const float dp2 = DP2[ibase];
  const float dt2 = DT2[ibase];
  const unsigned int ownP = (P[((size_t)b * NW + wj) * WW + y] >> bi) & 1u;
  const unsigned int ownT = (T[((size_t)b * NW + wj) * WW + y] >> bi) & 1u;

  __shared__ float4 s[WW];
  s[y] = make_float4(ownP ? 0.f : dp2, ownP ? dp2 : 0.f,
                     ownT ? 0.f : dt2, ownT ? dt2 : 0.f);
  __syncthreads();

  float4 me = s[y];
  float m0 = me.x, m1 = me.y, m2 = me.z, m3 = me.w;

  for (int k = 1; k < WW; ++k) {
    float c = (float)(k * k);
    float mx = fmaxf(fmaxf(m0, m1), fmaxf(m2, m3));
    if (c >= mx) break;                   // exact: remaining candidates >= k^2
    int lo = y - k;
    if (lo >= 0) {
      float4 v = s[lo];
      m0 = fminf(m0, v.x + c); m1 = fminf(m1, v.y + c);
      m2 = fminf(m2, v.z + c); m3 = fminf(m3, v.w + c);
    }
    int hic = y + k;
    if (hic < WW) {
      float4 v = s[hic];
      m0 = fminf(m0, v.x + c); m1 = fminf(m1, v.y + c);
      m2 = fminf(m2, v.z + c); m3 = fminf(m3, v.w + c);
    }
  }

  float pd = sqrtf(m0) + sqrtf(m1);       // pred_dist
  float td = sqrtf(m2) + sqrtf(m3);       // target_dist
  float diff = pd - td;
  float val = diff * diff * td * td;      // (pd-td)^2 * td^ALPHA, ALPHA=2

  for (int off = 32; off > 0; off >>= 1) val += __shfl_down(val, off);
  __shared__ float wsum[4];
  if ((threadIdx.x & 63) == 0) wsum[threadIdx.x >> 6] = val;
  __syncthreads();
  if (threadIdx.x == 0)
    partial[row] = (wsum[0] + wsum[1]) + (wsum[2] + wsum[3]);
}

// ---------------------------------------------------------------------------
// Kernel C: reduce 8192 row partials in double, write mean.
// ---------------------------------------------------------------------------
__global__ __launch_bounds__(256) void finalize_kernel(
    const float* __restrict__ partial, float* __restrict__ out) {
  __shared__ double sd[256];
  double sum = 0.0;
  for (int i = threadIdx.x; i < BB * HH; i += 256) sum += (double)partial[i];
  sd[threadIdx.x] = sum;
  __syncthreads();
  for (int stride = 128; stride > 0; stride >>= 1) {
    if (threadIdx.x < stride) sd[threadIdx.x] += sd[threadIdx.x + stride];
    __syncthreads();
  }
  if (threadIdx.x == 0)
    out[0] = (float)(sd[0] / (double)((size_t)BB * HH * WW));
}

extern "C" void kernel_launch(void* const* d_in, const int* in_sizes, int n_in,
                              void* d_out, int out_size, void* d_ws, size_t ws_size,
                              hipStream_t stream) {
  const float* pred = (const float*)d_in[0];
  const float* tgt  = (const float*)d_in[1];
  float* out = (float*)d_out;

  // ws: P (256 KB), T (256 KB), DP2 (8 MB), DT2 (8 MB), partial (32 KB)
  unsigned int* P = (unsigned int*)d_ws;
  unsigned int* T = P + (size_t)BB * NW * WW;
  float* DP2 = (float*)(T + (size_t)BB * NW * WW);
  float* DT2 = DP2 + (size_t)BB * HH * WW;
  float* partial = DT2 + (size_t)BB * HH * WW;

  hipLaunchKernelGGL(bitmask_kernel, dim3(BB * NW * 4), dim3(256), 0, stream,
                     pred, tgt, P, T);
  hipLaunchKernelGGL(coledt_kernel, dim3(BB * 16), dim3(256), 0, stream,
                     P, T, DP2, DT2);
  hipLaunchKernelGGL(minplus_kernel, dim3(BB * HH), dim3(256), 0, stream,
                     P, T, DP2, DT2, partial);
  hipLaunchKernelGGL(finalize_kernel, dim3(1), dim3(256), 0, stream,
                     partial, out);
}